// Round 1
// baseline (410.266 us; speedup 1.0000x reference)
//
#include <hip/hip_runtime.h>

#define NBAGS 4096
#define D_DIM 256   // columns; each of 64 lanes handles a float4

// ---------- CSR build ----------
__global__ void hist_kernel(const int* __restrict__ idx, int* __restrict__ counts, int n) {
    int i = blockIdx.x * blockDim.x + threadIdx.x;
    if (i < n) atomicAdd(&counts[idx[i]], 1);
}

__global__ void __launch_bounds__(1024) scan_kernel(const int* __restrict__ counts,
                                                    int* __restrict__ offsets) {
    // NBAGS=4096, 1024 threads x 4 elems each; Hillis-Steele on per-thread totals.
    __shared__ int sums[1024];
    int t = threadIdx.x;
    int c0 = counts[t*4+0], c1 = counts[t*4+1], c2 = counts[t*4+2], c3 = counts[t*4+3];
    int total = c0 + c1 + c2 + c3;
    sums[t] = total;
    __syncthreads();
    for (int off = 1; off < 1024; off <<= 1) {
        int v = (t >= off) ? sums[t - off] : 0;
        __syncthreads();
        sums[t] += v;
        __syncthreads();
    }
    int excl = sums[t] - total;   // exclusive prefix of totals
    offsets[t*4+0] = excl;
    offsets[t*4+1] = excl + c0;
    offsets[t*4+2] = excl + c0 + c1;
    offsets[t*4+3] = excl + c0 + c1 + c2;
    if (t == 1023) offsets[NBAGS] = excl + total;   // == n
}

__global__ void fill_csr_kernel(const int* __restrict__ idx, const int* __restrict__ offsets,
                                int* __restrict__ cursor, int* __restrict__ rows, int n) {
    int i = blockIdx.x * blockDim.x + threadIdx.x;
    if (i < n) {
        int s = idx[i];
        int p = atomicAdd(&cursor[s], 1);
        rows[offsets[s] + p] = i;
    }
}

// ---------- Pass A: sigma1[s,d] = (1/N) * sum_{i in bag s} nodes[i,d] ----------
__global__ void __launch_bounds__(64) pass_sum_kernel(const float* __restrict__ nodes,
        const int* __restrict__ rows, const int* __restrict__ offsets,
        float* __restrict__ S, float inv_n) {
    int s = blockIdx.x;
    int lane = threadIdx.x;
    int beg = offsets[s], end = offsets[s+1];
    const float4* nodes4 = (const float4*)nodes;
    float4 acc = make_float4(0.f, 0.f, 0.f, 0.f);
    __shared__ int ridx[64];
    for (int base = beg; base < end; base += 64) {
        int cnt = end - base; if (cnt > 64) cnt = 64;
        if (lane < cnt) ridx[lane] = rows[base + lane];
        __syncthreads();
        #pragma unroll 4
        for (int j = 0; j < cnt; ++j) {
            float4 v = nodes4[(size_t)ridx[j] * 64 + lane];
            acc.x += v.x; acc.y += v.y; acc.z += v.z; acc.w += v.w;
        }
        __syncthreads();
    }
    float4 o = make_float4(acc.x*inv_n, acc.y*inv_n, acc.z*inv_n, acc.w*inv_n);
    ((float4*)S)[(size_t)s * 64 + lane] = o;
}

// ---------- Pass B/C: per-bag coef c = C[s,d]; U = sum e*v, Zpart = sum e, e = exp(v*c) ----------
__global__ void __launch_bounds__(64) pass_exp_kernel(const float* __restrict__ nodes,
        const int* __restrict__ rows, const int* __restrict__ offsets,
        const float* __restrict__ C, float* __restrict__ U, float* __restrict__ Zp) {
    int s = blockIdx.x;
    int lane = threadIdx.x;
    int beg = offsets[s], end = offsets[s+1];
    const float4* nodes4 = (const float4*)nodes;
    float4 c = ((const float4*)C)[(size_t)s * 64 + lane];
    float4 u = make_float4(0.f, 0.f, 0.f, 0.f);
    float4 z = make_float4(0.f, 0.f, 0.f, 0.f);
    __shared__ int ridx[64];
    for (int base = beg; base < end; base += 64) {
        int cnt = end - base; if (cnt > 64) cnt = 64;
        if (lane < cnt) ridx[lane] = rows[base + lane];
        __syncthreads();
        #pragma unroll 4
        for (int j = 0; j < cnt; ++j) {
            float4 v = nodes4[(size_t)ridx[j] * 64 + lane];
            // |v*c| ~ 1e-3 -> exp safe without max subtraction (softmax shift-invariant)
            float ex = __expf(v.x * c.x); u.x += ex * v.x; z.x += ex;
            float ey = __expf(v.y * c.y); u.y += ey * v.y; z.y += ey;
            float ez = __expf(v.z * c.z); u.z += ez * v.z; z.z += ez;
            float ew = __expf(v.w * c.w); u.w += ew * v.w; z.w += ew;
        }
        __syncthreads();
    }
    ((float4*)U )[(size_t)s * 64 + lane] = u;
    ((float4*)Zp)[(size_t)s * 64 + lane] = z;
}

// ---------- column sum: Z[d] += sum over 16 bags of P[s,d] ----------
__global__ void __launch_bounds__(256) colsum_kernel(const float* __restrict__ P,
                                                     float* __restrict__ Z) {
    int d = threadIdx.x;
    int s0 = blockIdx.x * 16;
    float acc = 0.f;
    #pragma unroll
    for (int j = 0; j < 16; ++j) acc += P[(size_t)(s0 + j) * D_DIM + d];
    atomicAdd(&Z[d], acc);   // 256 blocks per address -> negligible contention
}

// ---------- S += U / Z (T2 = sigma1 + sigma2) ----------
__global__ void __launch_bounds__(256) update_kernel(float* __restrict__ S,
        const float* __restrict__ U, const float* __restrict__ Z) {
    int i = blockIdx.x * 256 + threadIdx.x;   // grid covers NBAGS*256 exactly
    S[i] += U[i] / Z[threadIdx.x];
}

// ---------- out = U / Z ----------
__global__ void __launch_bounds__(256) norm_kernel(float* __restrict__ out,
                                                   const float* __restrict__ Z) {
    int i = blockIdx.x * 256 + threadIdx.x;
    out[i] /= Z[threadIdx.x];
}

extern "C" void kernel_launch(void* const* d_in, const int* in_sizes, int n_in,
                              void* d_out, int out_size, void* d_ws, size_t ws_size,
                              hipStream_t stream) {
    const float* nodes  = (const float*)d_in[0];
    const int*   indices = (const int*)d_in[1];
    int n = in_sizes[1];                       // 200000 rows
    // D fixed at 256, NBAGS fixed at 4096 (per reference).

    // ---- workspace layout (all 256B-aligned) ----
    char* ws = (char*)d_ws;
    float* S       = (float*)ws;                                  // 4 MB coefficients
    float* scratch = (float*)(ws + (4u << 20));                   // 4 MB Zpart
    int*   rows    = (int*)  (ws + (8u << 20));                   // n ints
    size_t rows_b  = ((size_t)n * 4 + 255) & ~(size_t)255;
    int*   offsets = (int*)  (ws + (8u << 20) + rows_b);          // 4097 ints -> pad 16640
    char*  zreg    =          ws + (8u << 20) + rows_b + 16640;
    int*   counts  = (int*)zreg;                                  // 4096 ints
    int*   cursor  = (int*)(zreg + NBAGS * 4);                    // 4096 ints
    float* Z2      = (float*)(zreg + 2 * NBAGS * 4);              // 256 f
    float* Z3      = (float*)(zreg + 2 * NBAGS * 4 + 1024);       // 256 f
    size_t zbytes  = 2 * NBAGS * 4 + 2048;
    (void)ws_size; (void)n_in; (void)out_size;

    hipMemsetAsync(zreg, 0, zbytes, stream);

    int nb = (n + 255) / 256;
    hist_kernel    <<<nb, 256, 0, stream>>>(indices, counts, n);
    scan_kernel    <<<1, 1024, 0, stream>>>(counts, offsets);
    fill_csr_kernel<<<nb, 256, 0, stream>>>(indices, offsets, cursor, rows, n);

    float* U = (float*)d_out;   // reuse output as the U accumulator

    // iter 1: sigma1
    pass_sum_kernel<<<NBAGS, 64, 0, stream>>>(nodes, rows, offsets, S, 1.0f / (float)n);
    // iter 2: U2, Z2 -> S = sigma1 + U2/Z2
    pass_exp_kernel<<<NBAGS, 64, 0, stream>>>(nodes, rows, offsets, S, U, scratch);
    colsum_kernel  <<<NBAGS / 16, 256, 0, stream>>>(scratch, Z2);
    update_kernel  <<<NBAGS, 256, 0, stream>>>(S, U, Z2);
    // iter 3: U3, Z3 -> out = U3/Z3
    pass_exp_kernel<<<NBAGS, 64, 0, stream>>>(nodes, rows, offsets, S, U, scratch);
    colsum_kernel  <<<NBAGS / 16, 256, 0, stream>>>(scratch, Z3);
    norm_kernel    <<<NBAGS, 256, 0, stream>>>(U, Z3);
}